// Round 2
// baseline (339.630 us; speedup 1.0000x reference)
//
#include <hip/hip_runtime.h>
#include <hip/hip_bf16.h>

// IWHT3Layer: 3 branches of (per-coeff matmul [16,12544,64]x[16,64,64]) +
// inverse 2D 4x4 WHT over the 16 coefficients + bias.
// Inputs: float32. Output: float32.
//
// R6 change vs R5 (108us iwht dispatch, MfmaUtil 1.7%, VALUBusy 8%, HBM 27%,
// occupancy fix was a no-op): all pipes idle -> time lives in the per-chunk
// vmcnt(0) drains at __syncthreads. The x-tile is 64KB/block and re-read 4x
// by the block's waves -> L1/L2 absorb it (Common-mistake #7: don't LDS-stage
// cache-fit data). So: NO LDS, NO DMA, NO barriers. Each thread loads its x
// fragment directly from global (4x dwordx4 per t, fully coalesced: every
// touched 64B line is covered by exactly 2 lanes' 16B), 16 t unrolled so the
// compiler software-pipelines the independent loads with counted vmcnt.
// Fragment construction, MFMA operand order (A=weights, B=x -> C^T), WHT and
// epilogue are byte-identical to the verified R5 kernel.

typedef __attribute__((ext_vector_type(8))) short bf16x8;   // 8 bf16 (4 VGPRs)
typedef __attribute__((ext_vector_type(4))) float floatx4;  // MFMA C/D

#define NSITES 12544
#define NTILES 784
#define OUT_PER_BRANCH 12845056  // 16*112*112*64
#define WT_ELEMS (3*16*64*64)

__device__ __forceinline__ short f32_to_bf16_bits(float f) {
    __hip_bfloat16 h = __float2bfloat16(f);  // RNE
    return *reinterpret_cast<short*>(&h);
}

__global__ void transpose_weights(const float* __restrict__ w0,
                                  const float* __restrict__ w1,
                                  const float* __restrict__ w2,
                                  __hip_bfloat16* __restrict__ wT) {
    int idx = blockIdx.x * blockDim.x + threadIdx.x;  // [0, 3*16*64*64)
    if (idx >= WT_ELEMS) return;
    int c  = idx & 63;
    int k  = (idx >> 6) & 63;
    int t  = (idx >> 12) & 15;
    int br = idx >> 16;
    const float* w = (br == 0) ? w0 : ((br == 1) ? w1 : w2);
    // wT[br][t][k][c] = bf16(w[br][t][c][k])
    wT[idx] = __float2bfloat16(w[(t * 64 + c) * 64 + k]);
}

template <bool USE_WT>
__global__ __launch_bounds__(256, 3) void iwht_kernel(
    const float* __restrict__ x0, const float* __restrict__ x1,
    const float* __restrict__ x2,
    const float* __restrict__ w0, const float* __restrict__ w1,
    const float* __restrict__ w2,
    const __hip_bfloat16* __restrict__ wT,
    const float* __restrict__ b0, const float* __restrict__ b1,
    const float* __restrict__ b2,
    float* __restrict__ out) {
    int bx   = blockIdx.x;
    int br   = bx / NTILES;
    int tile = bx - br * NTILES;
    int lane = threadIdx.x & 63;
    int wave = threadIdx.x >> 6;
    int l15  = lane & 15;
    int quad = lane >> 4;
    int n    = wave * 16 + l15;  // weight-fragment row: output channel block

    const float* x    = (br == 0) ? x0 : ((br == 1) ? x1 : x2);
    const float* w    = (br == 0) ? w0 : ((br == 1) ? w1 : w2);
    const float* bias = (br == 0) ? b0 : ((br == 1) ? b1 : b2);

    // Per-lane x base: site row l15 of this tile, columns quad*8.. (+32).
    // x element layout: x[t][site][c], row stride 64 floats = 256B.
    const float* xb = x + ((size_t)(tile * 16 + l15)) * 64 + quad * 8;

    floatx4 acc[16];
#pragma unroll
    for (int t = 0; t < 16; t++) acc[t] = (floatx4){0.f, 0.f, 0.f, 0.f};

#pragma unroll
    for (int t = 0; t < 16; t++) {
        // x fragment (MFMA B operand), direct from global:
        // c = quad*8..+7 and quad*8+32..+39 (four 16B dwordx4 loads).
        const float* xr = xb + (size_t)t * (NSITES * 64);
        floatx4 f0 = ((const floatx4*)xr)[0];
        floatx4 f1 = ((const floatx4*)xr)[1];
        floatx4 f2 = ((const floatx4*)(xr + 32))[0];
        floatx4 f3 = ((const floatx4*)(xr + 32))[1];
        bf16x8 a0, a1;
#pragma unroll
        for (int j = 0; j < 4; j++) {
            a0[j]     = f32_to_bf16_bits(f0[j]);
            a0[j + 4] = f32_to_bf16_bits(f1[j]);
            a1[j]     = f32_to_bf16_bits(f2[j]);
            a1[j + 4] = f32_to_bf16_bits(f3[j]);
        }
        bf16x8 bb0, bb1;
        if (USE_WT) {
            // weight fragment (MFMA A operand):
            // wT[br][t][n][c] bf16, same c<->lane mapping as x fragment
            const bf16x8* wv = reinterpret_cast<const bf16x8*>(
                wT + (((size_t)(br * 16 + t) * 64 + n) * 64) + quad * 8);
            bb0 = wv[0];
            bb1 = wv[4];  // +32 c elements
        } else {
            // fallback: strided f32 loads from original w[t][c][k]
#pragma unroll
            for (int j = 0; j < 8; j++) {
                int c0 = quad * 8 + j;
                bb0[j] = f32_to_bf16_bits(w[(t * 64 + c0) * 64 + n]);
                bb1[j] = f32_to_bf16_bits(w[(t * 64 + c0 + 32) * 64 + n]);
            }
        }
        // D = W * X -> D[row=k, col=site].
        // Thread (wave,quad,l15,reg) holds y[t][site=tile*16+l15]
        //                                     [k = wave*16 + quad*4 + reg]
        acc[t] = __builtin_amdgcn_mfma_f32_16x16x32_bf16(bb0, a0, acc[t], 0, 0, 0);
        acc[t] = __builtin_amdgcn_mfma_f32_16x16x32_bf16(bb1, a1, acc[t], 0, 0, 0);
    }

    // Epilogue: one site per thread, 4 consecutive k per reg -> float4 stores.
    int k0   = wave * 16 + quad * 4;
    int site = tile * 16 + l15;
    int b    = site / 784;
    int rem  = site - b * 784;
    int i    = rem / 28;
    int j    = rem - i * 28;
    float* op = out + (size_t)br * OUT_PER_BRANCH +
                (((size_t)(b * 112 + 4 * i)) * 112 + 4 * j) * 64 + k0;
    floatx4 bias4 = *reinterpret_cast<const floatx4*>(bias + k0);

    // Inverse WHT over v (t = 4u+v): acc[4u+q] = sum_v H[q][v] y[4u+v]
#pragma unroll
    for (int u = 0; u < 4; u++) {
        floatx4 y0 = acc[4 * u + 0], y1 = acc[4 * u + 1];
        floatx4 y2 = acc[4 * u + 2], y3 = acc[4 * u + 3];
        floatx4 A = y0 + y2, Bv = y1 + y3, Cv = y0 - y2, Dv = y1 - y3;
        acc[4 * u + 0] = A + Bv;
        acc[4 * u + 1] = A - Bv;
        acc[4 * u + 2] = Cv + Dv;
        acc[4 * u + 3] = Cv - Dv;
    }

    // Inverse WHT over u, then scale + bias + vectorized store (dwordx4).
#pragma unroll
    for (int q = 0; q < 4; q++) {
        floatx4 z0 = acc[0 + q], z1 = acc[4 + q], z2 = acc[8 + q], z3 = acc[12 + q];
        floatx4 A = z0 + z2, Bv = z1 + z3, Cv = z0 - z2, Dv = z1 - z3;
        floatx4 o[4];
        o[0] = A + Bv;
        o[1] = A - Bv;
        o[2] = Cv + Dv;
        o[3] = Cv - Dv;
#pragma unroll
        for (int p = 0; p < 4; p++) {
            floatx4 v = o[p] * 0.0625f + bias4;
            *reinterpret_cast<floatx4*>(op + (size_t)(p * 112 + q) * 64) = v;
        }
    }
}

extern "C" void kernel_launch(void* const* d_in, const int* in_sizes, int n_in,
                              void* d_out, int out_size, void* d_ws, size_t ws_size,
                              hipStream_t stream) {
    const float* x0 = (const float*)d_in[0];
    const float* x1 = (const float*)d_in[1];
    const float* x2 = (const float*)d_in[2];
    const float* w0 = (const float*)d_in[3];
    const float* w1 = (const float*)d_in[4];
    const float* w2 = (const float*)d_in[5];
    const float* b0 = (const float*)d_in[6];
    const float* b1 = (const float*)d_in[7];
    const float* b2 = (const float*)d_in[8];
    float* out = (float*)d_out;
    __hip_bfloat16* wT = (__hip_bfloat16*)d_ws;

    bool use_wt = ws_size >= (size_t)WT_ELEMS * sizeof(__hip_bfloat16);
    if (use_wt) {
        transpose_weights<<<(WT_ELEMS + 255) / 256, 256, 0, stream>>>(w0, w1, w2, wT);
        iwht_kernel<true><<<3 * NTILES, 256, 0, stream>>>(x0, x1, x2, w0, w1, w2, wT,
                                                          b0, b1, b2, out);
    } else {
        iwht_kernel<false><<<3 * NTILES, 256, 0, stream>>>(x0, x1, x2, w0, w1, w2, wT,
                                                           b0, b1, b2, out);
    }
}

// Round 3
// 298.344 us; speedup vs baseline: 1.1384x; 1.1384x over previous
//
#include <hip/hip_runtime.h>
#include <hip/hip_bf16.h>

// IWHT3Layer: 3 branches of (per-coeff matmul [16,12544,64]x[16,64,64]) +
// inverse 2D 4x4 WHT over the 16 coefficients + bias.
// Inputs: float32. Output: float32.
//
// R7 change vs R5 (108us, all pipes idle) and R6 (146us, direct-global
// REGRESSION -> reverted): R5's __syncthreads() per chunk forces
// s_waitcnt vmcnt(0), draining the chunk-(g+1) DMAs issued the same
// iteration -> every chunk boundary exposes a full HBM round trip (the
// classic barrier-drain pathology; fix = T3/T4 counted vmcnt).
// New sync structure:
//   - 3-deep chunk ring (LDS 3x17408B = 52224B -> 3 blocks/CU),
//   - stage chunks 0,1,2 up front (48 width-4 DMAs/wave in flight),
//   - per phase g: s_waitcnt vmcnt(16*chunks_still_in_flight) +
//     raw s_barrier (NO vmcnt(0) drain), compute chunk g,
//   - after phase 0 only: barrier (buf0 consumers done) + stage chunk 3
//     into buf 0.
// DMA pattern (coalesced 256B/wave width-4), fragment construction, MFMA
// operand order (A=weights, B=x -> C^T), WHT and epilogue are byte-identical
// to the verified R5 kernel.

typedef __attribute__((ext_vector_type(8))) short bf16x8;   // 8 bf16 (4 VGPRs)
typedef __attribute__((ext_vector_type(4))) float floatx4;  // MFMA C/D

#define NSITES 12544
#define NTILES 784
#define OUT_PER_BRANCH 12845056  // 16*112*112*64
#define WT_ELEMS (3*16*64*64)
#define ROW_F 68                 // LDS row stride in floats: 64 data + 4 pad
#define CHUNK_F (64 * ROW_F)     // 4 t * 16 rows = 64 rows per chunk (17408 B)

__device__ __forceinline__ short f32_to_bf16_bits(float f) {
    __hip_bfloat16 h = __float2bfloat16(f);  // RNE
    return *reinterpret_cast<short*>(&h);
}

__global__ void transpose_weights(const float* __restrict__ w0,
                                  const float* __restrict__ w1,
                                  const float* __restrict__ w2,
                                  __hip_bfloat16* __restrict__ wT) {
    int idx = blockIdx.x * blockDim.x + threadIdx.x;  // [0, 3*16*64*64)
    if (idx >= WT_ELEMS) return;
    int c  = idx & 63;
    int k  = (idx >> 6) & 63;
    int t  = (idx >> 12) & 15;
    int br = idx >> 16;
    const float* w = (br == 0) ? w0 : ((br == 1) ? w1 : w2);
    // wT[br][t][k][c] = bf16(w[br][t][c][k])
    wT[idx] = __float2bfloat16(w[(t * 64 + c) * 64 + k]);
}

template <bool USE_WT>
__global__ __launch_bounds__(256, 3) void iwht_kernel(
    const float* __restrict__ x0, const float* __restrict__ x1,
    const float* __restrict__ x2,
    const float* __restrict__ w0, const float* __restrict__ w1,
    const float* __restrict__ w2,
    const __hip_bfloat16* __restrict__ wT,
    const float* __restrict__ b0, const float* __restrict__ b1,
    const float* __restrict__ b2,
    float* __restrict__ out) {
    __shared__ float xs[3][CHUNK_F];  // 3 x 17408 B = 52224 B

    int bx   = blockIdx.x;
    int br   = bx / NTILES;
    int tile = bx - br * NTILES;
    int lane = threadIdx.x & 63;
    int wave = threadIdx.x >> 6;
    int l15  = lane & 15;
    int quad = lane >> 4;
    int n    = wave * 16 + l15;  // weight-fragment row: output channel block

    const float* x    = (br == 0) ? x0 : ((br == 1) ? x1 : x2);
    const float* w    = (br == 0) ? w0 : ((br == 1) ? w1 : w2);
    const float* bias = (br == 0) ? b0 : ((br == 1) ? b1 : b2);

    // DMA source base: row (t, s) starts at x + (t*NSITES + tile*16 + s)*64;
    // lane contributes 4 bytes at +lane (64 consecutive lanes = 256B/row).
    const float* xg = x + (size_t)(tile * 16) * 64 + lane;

    floatx4 acc[16];
#pragma unroll
    for (int t = 0; t < 16; t++) acc[t] = (floatx4){0.f, 0.f, 0.f, 0.f};

    // --- stage chunk g (t = 4g..4g+3) into xs[buf]: wave handles 16 rows ---
#define STAGE(g, buf)                                                          \
    {                                                                          \
        _Pragma("unroll") for (int r = 0; r < 16; r++) {                       \
            int row = wave * 16 + r; /* row = tl*16 + s */                     \
            int tl  = row >> 4;                                                \
            int s   = row & 15;                                                \
            const float* gp = xg + ((size_t)((g) * 4 + tl) * NSITES + s) * 64; \
            __builtin_amdgcn_global_load_lds(                                  \
                (const __attribute__((address_space(1))) void*)gp,             \
                (__attribute__((address_space(3))) void*)&xs[buf][row * ROW_F],\
                4, 0, 0);                                                      \
        }                                                                      \
    }

    // --- compute chunk g from xs[buf]: 4 t-planes, 2 MFMA each ---
#define COMPUTE(g, buf)                                                        \
    {                                                                          \
        _Pragma("unroll") for (int tl = 0; tl < 4; tl++) {                     \
            int t = (g) * 4 + tl;                                              \
            const float* rowp = &xs[buf][(tl * 16 + l15) * ROW_F + quad * 8];  \
            floatx4 f0 = ((const floatx4*)rowp)[0];                            \
            floatx4 f1 = ((const floatx4*)rowp)[1];                            \
            floatx4 f2 = ((const floatx4*)(rowp + 32))[0];                     \
            floatx4 f3 = ((const floatx4*)(rowp + 32))[1];                     \
            bf16x8 a0, a1;                                                     \
            _Pragma("unroll") for (int j = 0; j < 4; j++) {                    \
                a0[j]     = f32_to_bf16_bits(f0[j]);                           \
                a0[j + 4] = f32_to_bf16_bits(f1[j]);                           \
                a1[j]     = f32_to_bf16_bits(f2[j]);                           \
                a1[j + 4] = f32_to_bf16_bits(f3[j]);                           \
            }                                                                  \
            bf16x8 bb0, bb1;                                                   \
            if (USE_WT) {                                                      \
                const bf16x8* wv = reinterpret_cast<const bf16x8*>(            \
                    wT + (((size_t)(br * 16 + t) * 64 + n) * 64) + quad * 8);  \
                bb0 = wv[0];                                                   \
                bb1 = wv[4];                                                   \
            } else {                                                           \
                _Pragma("unroll") for (int j = 0; j < 8; j++) {                \
                    int c0 = quad * 8 + j;                                     \
                    bb0[j] = f32_to_bf16_bits(w[(t * 64 + c0) * 64 + n]);      \
                    bb1[j] = f32_to_bf16_bits(w[(t * 64 + c0 + 32) * 64 + n]); \
                }                                                              \
            }                                                                  \
            acc[t] = __builtin_amdgcn_mfma_f32_16x16x32_bf16(bb0, a0, acc[t],  \
                                                             0, 0, 0);         \
            acc[t] = __builtin_amdgcn_mfma_f32_16x16x32_bf16(bb1, a1, acc[t],  \
                                                             0, 0, 0);         \
        }                                                                      \
    }

#define WAITV(N)                                                               \
    asm volatile("s_waitcnt vmcnt(" #N ")" ::: "memory");                      \
    __builtin_amdgcn_s_barrier();                                              \
    __builtin_amdgcn_sched_barrier(0);

    // Prologue: 3 chunks in flight (48 DMA insts/wave, 48KB of this block's
    // 64KB tile requested before any wait).
    STAGE(0, 0);
    STAGE(1, 1);
    STAGE(2, 2);

    // Phase 0: chunk 0 ready when <=32 of our 48 DMAs remain.
    WAITV(32);
    COMPUTE(0, 0);
    // buf0 consumers done across all waves -> safe to restage into buf0.
    __builtin_amdgcn_s_barrier();
    STAGE(3, 0);  // outstanding <= 32 + 16 = 48

    // Phase 1: chunk 1 ready when <=32 remain (S2 + S3 still allowed in flight).
    WAITV(32);
    COMPUTE(1, 1);

    // Phase 2: chunk 2 ready when <=16 remain (S3 in flight).
    WAITV(16);
    COMPUTE(2, 2);

    // Phase 3: chunk 3 (issued 3 compute-phases ago) fully landed.
    WAITV(0);
    COMPUTE(3, 0);

#undef STAGE
#undef COMPUTE
#undef WAITV

    // Epilogue: one site per thread, 4 consecutive k per reg -> float4 stores.
    int k0   = wave * 16 + quad * 4;
    int site = tile * 16 + l15;
    int b    = site / 784;
    int rem  = site - b * 784;
    int i    = rem / 28;
    int j    = rem - i * 28;
    float* op = out + (size_t)br * OUT_PER_BRANCH +
                (((size_t)(b * 112 + 4 * i)) * 112 + 4 * j) * 64 + k0;
    floatx4 bias4 = *reinterpret_cast<const floatx4*>(bias + k0);

    // Inverse WHT over v (t = 4u+v): acc[4u+q] = sum_v H[q][v] y[4u+v]
#pragma unroll
    for (int u = 0; u < 4; u++) {
        floatx4 y0 = acc[4 * u + 0], y1 = acc[4 * u + 1];
        floatx4 y2 = acc[4 * u + 2], y3 = acc[4 * u + 3];
        floatx4 A = y0 + y2, Bv = y1 + y3, Cv = y0 - y2, Dv = y1 - y3;
        acc[4 * u + 0] = A + Bv;
        acc[4 * u + 1] = A - Bv;
        acc[4 * u + 2] = Cv + Dv;
        acc[4 * u + 3] = Cv - Dv;
    }

    // Inverse WHT over u, then scale + bias + vectorized store (dwordx4).
#pragma unroll
    for (int q = 0; q < 4; q++) {
        floatx4 z0 = acc[0 + q], z1 = acc[4 + q], z2 = acc[8 + q], z3 = acc[12 + q];
        floatx4 A = z0 + z2, Bv = z1 + z3, Cv = z0 - z2, Dv = z1 - z3;
        floatx4 o[4];
        o[0] = A + Bv;
        o[1] = A - Bv;
        o[2] = Cv + Dv;
        o[3] = Cv - Dv;
#pragma unroll
        for (int p = 0; p < 4; p++) {
            floatx4 v = o[p] * 0.0625f + bias4;
            *reinterpret_cast<floatx4*>(op + (size_t)(p * 112 + q) * 64) = v;
        }
    }
}

extern "C" void kernel_launch(void* const* d_in, const int* in_sizes, int n_in,
                              void* d_out, int out_size, void* d_ws, size_t ws_size,
                              hipStream_t stream) {
    const float* x0 = (const float*)d_in[0];
    const float* x1 = (const float*)d_in[1];
    const float* x2 = (const float*)d_in[2];
    const float* w0 = (const float*)d_in[3];
    const float* w1 = (const float*)d_in[4];
    const float* w2 = (const float*)d_in[5];
    const float* b0 = (const float*)d_in[6];
    const float* b1 = (const float*)d_in[7];
    const float* b2 = (const float*)d_in[8];
    float* out = (float*)d_out;
    __hip_bfloat16* wT = (__hip_bfloat16*)d_ws;

    bool use_wt = ws_size >= (size_t)WT_ELEMS * sizeof(__hip_bfloat16);
    if (use_wt) {
        transpose_weights<<<(WT_ELEMS + 255) / 256, 256, 0, stream>>>(w0, w1, w2, wT);
        iwht_kernel<true><<<3 * NTILES, 256, 0, stream>>>(x0, x1, x2, w0, w1, w2, wT,
                                                          b0, b1, b2, out);
    } else {
        iwht_kernel<false><<<3 * NTILES, 256, 0, stream>>>(x0, x1, x2, w0, w1, w2, wT,
                                                           b0, b1, b2, out);
    }
}

// Round 4
// 296.315 us; speedup vs baseline: 1.1462x; 1.0068x over previous
//
#include <hip/hip_runtime.h>
#include <hip/hip_bf16.h>

// IWHT3Layer: 3 branches of (per-coeff matmul [16,12544,64]x[16,64,64]) +
// inverse 2D 4x4 WHT over the 16 coefficients + bias.
// Inputs: float32. Output: float32.
//
// R8 change vs R7 (112us; R4/R5/R6/R7 all ~110us, 2.1TB/s -> load-latency
// theories dead, wall is a RATE limit): the invariant across rounds was the
// width-4 global_load_lds (256B/inst, 64 insts/wave). Precedent m93->m97:
// width 4->16 = +69% in a staging-bound GEMM. Now: width-16 DMA, 1KB/inst
// (4 contiguous 256B site-rows), 16 DMA insts/wave. Width-16 requires a
// linear LDS dest (no row pad) -> ds_read would be 16-way bank-conflicted;
// fixed per T2/m173/rule#21: linear LDS + XOR-swizzled global SOURCE +
// same XOR on the read address (logical 16B col c of row r stored at
// c ^ (r&7); read 8 lanes/128B-slot x 8 slots = b128 minimum = conflict-free).
// Ring structure (3-deep, counted vmcnt, raw barriers), matmul, WHT and
// epilogue identical to verified R7.

typedef __attribute__((ext_vector_type(8))) short bf16x8;   // 8 bf16 (4 VGPRs)
typedef __attribute__((ext_vector_type(4))) float floatx4;  // MFMA C/D

#define NSITES 12544
#define NTILES 784
#define OUT_PER_BRANCH 12845056  // 16*112*112*64
#define WT_ELEMS (3*16*64*64)
#define CHUNK_F (64 * 64)        // 4 t * 16 rows * 64 floats = 16384 B per chunk

__device__ __forceinline__ short f32_to_bf16_bits(float f) {
    __hip_bfloat16 h = __float2bfloat16(f);  // RNE
    return *reinterpret_cast<short*>(&h);
}

__global__ void transpose_weights(const float* __restrict__ w0,
                                  const float* __restrict__ w1,
                                  const float* __restrict__ w2,
                                  __hip_bfloat16* __restrict__ wT) {
    int idx = blockIdx.x * blockDim.x + threadIdx.x;  // [0, 3*16*64*64)
    if (idx >= WT_ELEMS) return;
    int c  = idx & 63;
    int k  = (idx >> 6) & 63;
    int t  = (idx >> 12) & 15;
    int br = idx >> 16;
    const float* w = (br == 0) ? w0 : ((br == 1) ? w1 : w2);
    // wT[br][t][k][c] = bf16(w[br][t][c][k])
    wT[idx] = __float2bfloat16(w[(t * 64 + c) * 64 + k]);
}

template <bool USE_WT>
__global__ __launch_bounds__(256, 3) void iwht_kernel(
    const float* __restrict__ x0, const float* __restrict__ x1,
    const float* __restrict__ x2,
    const float* __restrict__ w0, const float* __restrict__ w1,
    const float* __restrict__ w2,
    const __hip_bfloat16* __restrict__ wT,
    const float* __restrict__ b0, const float* __restrict__ b1,
    const float* __restrict__ b2,
    float* __restrict__ out) {
    __shared__ float xs[3][CHUNK_F];  // 3 x 16384 B = 49152 B

    int bx   = blockIdx.x;
    int br   = bx / NTILES;
    int tile = bx - br * NTILES;
    int lane = threadIdx.x & 63;
    int wave = threadIdx.x >> 6;
    int l15  = lane & 15;
    int quad = lane >> 4;
    int n    = wave * 16 + l15;  // weight-fragment row: output channel block

    const float* x    = (br == 0) ? x0 : ((br == 1) ? x1 : x2);
    const float* w    = (br == 0) ? w0 : ((br == 1) ? w1 : w2);
    const float* bias = (br == 0) ? b0 : ((br == 1) ? b1 : b2);

    // Width-16 DMA lane decomposition: inst covers 4 site-rows (1KB);
    // lane serves sub-row (lane>>4), 16B column (lane&15), XOR-swizzled.
    int sub  = lane >> 4;   // 0..3: which of the 4 rows in this inst
    int lcol = lane & 15;   // 16B column within the 256B row

    floatx4 acc[16];
#pragma unroll
    for (int t = 0; t < 16; t++) acc[t] = (floatx4){0.f, 0.f, 0.f, 0.f};

    // --- stage chunk g (t = 4g..4g+3) into xs[buf] ---
    // Wave w stages t-plane (4g + w): 16 site-rows as 4 width-16 DMAs.
    // LDS layout: xs[buf][(tl*16 + s)*64 + col'*4], col' = col ^ (s & 7).
    // DMA dest is linear (base + lane*16B), so the SOURCE column is
    // pre-swizzled: lane fetches logical col (lane&15) ^ (row & 7).
#define STAGE(g, buf)                                                          \
    {                                                                          \
        _Pragma("unroll") for (int r = 0; r < 4; r++) {                        \
            int s   = 4 * r + sub;          /* site row within plane */        \
            int col = lcol ^ (s & 7);       /* swizzled 16B column   */        \
            const float* gp = x +                                              \
                ((size_t)((g) * 4 + wave) * NSITES + tile * 16 + s) * 64 +     \
                col * 4;                                                       \
            __builtin_amdgcn_global_load_lds(                                  \
                (const __attribute__((address_space(1))) void*)gp,             \
                (__attribute__((address_space(3))) void*)                      \
                    &xs[buf][(wave * 16 + 4 * r) * 64],                        \
                16, 0, 0);                                                     \
        }                                                                      \
    }

    // --- compute chunk g from xs[buf]: 4 t-planes, 2 MFMA each ---
    // Read with the same XOR: logical col c of row l15 is at c ^ (l15&7).
#define COMPUTE(g, buf)                                                        \
    {                                                                          \
        int xr7 = l15 & 7;                                                     \
        _Pragma("unroll") for (int tl = 0; tl < 4; tl++) {                     \
            int t = (g) * 4 + tl;                                              \
            const float* rp = &xs[buf][(tl * 16 + l15) * 64];                  \
            floatx4 f0 = *(const floatx4*)(rp + ((quad * 2) ^ xr7) * 4);       \
            floatx4 f1 = *(const floatx4*)(rp + ((quad * 2 + 1) ^ xr7) * 4);   \
            floatx4 f2 = *(const floatx4*)(rp + (((quad * 2) ^ xr7) + 8) * 4); \
            floatx4 f3 = *(const floatx4*)(rp + (((quad * 2 + 1) ^ xr7) + 8) * 4); \
            bf16x8 a0, a1;                                                     \
            _Pragma("unroll") for (int j = 0; j < 4; j++) {                    \
                a0[j]     = f32_to_bf16_bits(f0[j]);                           \
                a0[j + 4] = f32_to_bf16_bits(f1[j]);                           \
                a1[j]     = f32_to_bf16_bits(f2[j]);                           \
                a1[j + 4] = f32_to_bf16_bits(f3[j]);                           \
            }                                                                  \
            bf16x8 bb0, bb1;                                                   \
            if (USE_WT) {                                                      \
                const bf16x8* wv = reinterpret_cast<const bf16x8*>(            \
                    wT + (((size_t)(br * 16 + t) * 64 + n) * 64) + quad * 8);  \
                bb0 = wv[0];                                                   \
                bb1 = wv[4];                                                   \
            } else {                                                           \
                _Pragma("unroll") for (int j = 0; j < 8; j++) {                \
                    int c0 = quad * 8 + j;                                     \
                    bb0[j] = f32_to_bf16_bits(w[(t * 64 + c0) * 64 + n]);      \
                    bb1[j] = f32_to_bf16_bits(w[(t * 64 + c0 + 32) * 64 + n]); \
                }                                                              \
            }                                                                  \
            acc[t] = __builtin_amdgcn_mfma_f32_16x16x32_bf16(bb0, a0, acc[t],  \
                                                             0, 0, 0);         \
            acc[t] = __builtin_amdgcn_mfma_f32_16x16x32_bf16(bb1, a1, acc[t],  \
                                                             0, 0, 0);         \
        }                                                                      \
    }

#define WAITV(N)                                                               \
    asm volatile("s_waitcnt vmcnt(" #N ")" ::: "memory");                      \
    __builtin_amdgcn_s_barrier();                                              \
    __builtin_amdgcn_sched_barrier(0);

    // Prologue: 3 chunks in flight (12 width-16 DMAs/wave = this block's
    // entire 48KB front requested before any wait).
    STAGE(0, 0);
    STAGE(1, 1);
    STAGE(2, 2);

    // Phase 0: chunk 0 ready when <=8 of our 12 DMAs remain.
    WAITV(8);
    COMPUTE(0, 0);
    // buf0 consumers done across all waves -> safe to restage into buf0.
    __builtin_amdgcn_s_barrier();
    __builtin_amdgcn_sched_barrier(0);
    STAGE(3, 0);  // outstanding <= 8 + 4 = 12

    // Phase 1: chunk 1 ready when <=8 remain (c2 + c3 still in flight).
    WAITV(8);
    COMPUTE(1, 1);

    // Phase 2: chunk 2 ready when <=4 remain (c3 in flight).
    WAITV(4);
    COMPUTE(2, 2);

    // Phase 3: chunk 3 (issued 3 compute-phases ago) fully landed.
    WAITV(0);
    COMPUTE(3, 0);

#undef STAGE
#undef COMPUTE
#undef WAITV

    // Epilogue: one site per thread, 4 consecutive k per reg -> float4 stores.
    int k0   = wave * 16 + quad * 4;
    int site = tile * 16 + l15;
    int b    = site / 784;
    int rem  = site - b * 784;
    int i    = rem / 28;
    int j    = rem - i * 28;
    float* op = out + (size_t)br * OUT_PER_BRANCH +
                (((size_t)(b * 112 + 4 * i)) * 112 + 4 * j) * 64 + k0;
    floatx4 bias4 = *reinterpret_cast<const floatx4*>(bias + k0);

    // Inverse WHT over v (t = 4u+v): acc[4u+q] = sum_v H[q][v] y[4u+v]
#pragma unroll
    for (int u = 0; u < 4; u++) {
        floatx4 y0 = acc[4 * u + 0], y1 = acc[4 * u + 1];
        floatx4 y2 = acc[4 * u + 2], y3 = acc[4 * u + 3];
        floatx4 A = y0 + y2, Bv = y1 + y3, Cv = y0 - y2, Dv = y1 - y3;
        acc[4 * u + 0] = A + Bv;
        acc[4 * u + 1] = A - Bv;
        acc[4 * u + 2] = Cv + Dv;
        acc[4 * u + 3] = Cv - Dv;
    }

    // Inverse WHT over u, then scale + bias + vectorized store (dwordx4).
#pragma unroll
    for (int q = 0; q < 4; q++) {
        floatx4 z0 = acc[0 + q], z1 = acc[4 + q], z2 = acc[8 + q], z3 = acc[12 + q];
        floatx4 A = z0 + z2, Bv = z1 + z3, Cv = z0 - z2, Dv = z1 - z3;
        floatx4 o[4];
        o[0] = A + Bv;
        o[1] = A - Bv;
        o[2] = Cv + Dv;
        o[3] = Cv - Dv;
#pragma unroll
        for (int p = 0; p < 4; p++) {
            floatx4 v = o[p] * 0.0625f + bias4;
            *reinterpret_cast<floatx4*>(op + (size_t)(p * 112 + q) * 64) = v;
        }
    }
}

extern "C" void kernel_launch(void* const* d_in, const int* in_sizes, int n_in,
                              void* d_out, int out_size, void* d_ws, size_t ws_size,
                              hipStream_t stream) {
    const float* x0 = (const float*)d_in[0];
    const float* x1 = (const float*)d_in[1];
    const float* x2 = (const float*)d_in[2];
    const float* w0 = (const float*)d_in[3];
    const float* w1 = (const float*)d_in[4];
    const float* w2 = (const float*)d_in[5];
    const float* b0 = (const float*)d_in[6];
    const float* b1 = (const float*)d_in[7];
    const float* b2 = (const float*)d_in[8];
    float* out = (float*)d_out;
    __hip_bfloat16* wT = (__hip_bfloat16*)d_ws;

    bool use_wt = ws_size >= (size_t)WT_ELEMS * sizeof(__hip_bfloat16);
    if (use_wt) {
        transpose_weights<<<(WT_ELEMS + 255) / 256, 256, 0, stream>>>(w0, w1, w2, wT);
        iwht_kernel<true><<<3 * NTILES, 256, 0, stream>>>(x0, x1, x2, w0, w1, w2, wT,
                                                          b0, b1, b2, out);
    } else {
        iwht_kernel<false><<<3 * NTILES, 256, 0, stream>>>(x0, x1, x2, w0, w1, w2, wT,
                                                           b0, b1, b2, out);
    }
}

// Round 5
// 292.541 us; speedup vs baseline: 1.1610x; 1.0129x over previous
//
#include <hip/hip_runtime.h>
#include <hip/hip_bf16.h>

// IWHT3Layer: 3 branches of (per-coeff matmul [16,12544,64]x[16,64,64]) +
// inverse 2D 4x4 WHT over the 16 coefficients + bias.
// Inputs: float32. Output: float32.
//
// R9 change vs R8 (104us; R5/R7/R8 all ~105-110us): the counted-vmcnt ring
// never worked — vmcnt completion is IN ISSUE ORDER (m135: waits for the
// oldest ops), and the wT weight loads issued INSIDE each compute phase are
// the newest VMEM ops, so the compiler's own s_waitcnt before their MFMA use
// drains the whole DMA queue every phase (hidden vmcnt(0) per chunk).
// Fix: ZERO VMEM in the main loop. All 32 weight fragments (16t x 2 bf16x8 =
// 128 VGPRs) are loaded into registers ONCE at block start, ISSUED BEFORE the
// ring DMAs, so one counted wait covers {all wf, chunk0} and the ring counts
// are exact:
//   issue: wf(32) | S0 S1 S2 (12 DMA)          -> outstanding 44
//   WAITV(8): wf+S0 done (S1,S2 in flight) -> compute(0); barrier; S3->buf0
//   WAITV(8): S1 done  -> compute(1)
//   WAITV(4): S2 done  -> compute(2)
//   WAITV(0): S3 done  -> compute(3)
// __launch_bounds__(256,2): ~220 regs (128 wf + 64 acc + working), no spill.
// Width-16 swizzled DMA staging, LDS read swizzle, matmul, WHT and epilogue
// byte-identical to verified R8.

typedef __attribute__((ext_vector_type(8))) short bf16x8;   // 8 bf16 (4 VGPRs)
typedef __attribute__((ext_vector_type(4))) float floatx4;  // MFMA C/D

#define NSITES 12544
#define NTILES 784
#define OUT_PER_BRANCH 12845056  // 16*112*112*64
#define WT_ELEMS (3*16*64*64)
#define CHUNK_F (64 * 64)        // 4 t * 16 rows * 64 floats = 16384 B per chunk

__device__ __forceinline__ short f32_to_bf16_bits(float f) {
    __hip_bfloat16 h = __float2bfloat16(f);  // RNE
    return *reinterpret_cast<short*>(&h);
}

__global__ void transpose_weights(const float* __restrict__ w0,
                                  const float* __restrict__ w1,
                                  const float* __restrict__ w2,
                                  __hip_bfloat16* __restrict__ wT) {
    int idx = blockIdx.x * blockDim.x + threadIdx.x;  // [0, 3*16*64*64)
    if (idx >= WT_ELEMS) return;
    int c  = idx & 63;
    int k  = (idx >> 6) & 63;
    int t  = (idx >> 12) & 15;
    int br = idx >> 16;
    const float* w = (br == 0) ? w0 : ((br == 1) ? w1 : w2);
    // wT[br][t][k][c] = bf16(w[br][t][c][k])
    wT[idx] = __float2bfloat16(w[(t * 64 + c) * 64 + k]);
}

template <bool USE_WT>
__global__ __launch_bounds__(256, 2) void iwht_kernel(
    const float* __restrict__ x0, const float* __restrict__ x1,
    const float* __restrict__ x2,
    const float* __restrict__ w0, const float* __restrict__ w1,
    const float* __restrict__ w2,
    const __hip_bfloat16* __restrict__ wT,
    const float* __restrict__ b0, const float* __restrict__ b1,
    const float* __restrict__ b2,
    float* __restrict__ out) {
    __shared__ float xs[3][CHUNK_F];  // 3 x 16384 B = 49152 B

    int bx   = blockIdx.x;
    int br   = bx / NTILES;
    int tile = bx - br * NTILES;
    int lane = threadIdx.x & 63;
    int wave = threadIdx.x >> 6;
    int l15  = lane & 15;
    int quad = lane >> 4;
    int n    = wave * 16 + l15;  // weight-fragment row: output channel block

    const float* x    = (br == 0) ? x0 : ((br == 1) ? x1 : x2);
    const float* w    = (br == 0) ? w0 : ((br == 1) ? w1 : w2);
    const float* bias = (br == 0) ? b0 : ((br == 1) ? b1 : b2);

    // Width-16 DMA lane decomposition: inst covers 4 site-rows (1KB);
    // lane serves sub-row (lane>>4), 16B column (lane&15), XOR-swizzled.
    int sub  = lane >> 4;   // 0..3: which of the 4 rows in this inst
    int lcol = lane & 15;   // 16B column within the 256B row

    floatx4 acc[16];
#pragma unroll
    for (int t = 0; t < 16; t++) acc[t] = (floatx4){0.f, 0.f, 0.f, 0.f};

    // --- ALL weight fragments into registers, issued BEFORE any DMA so the
    // ring's counted vmcnt waits cover them (in-order completion). ---
    bf16x8 wf[32];  // wf[2t] = c 0..31? no: c quad*8..+7/+32..  (2 frags per t)
    if (USE_WT) {
#pragma unroll
        for (int t = 0; t < 16; t++) {
            const bf16x8* wv = reinterpret_cast<const bf16x8*>(
                wT + (((size_t)(br * 16 + t) * 64 + n) * 64) + quad * 8);
            wf[2 * t]     = wv[0];
            wf[2 * t + 1] = wv[4];  // +32 c elements
        }
    } else {
#pragma unroll
        for (int t = 0; t < 16; t++) {
#pragma unroll
            for (int j = 0; j < 8; j++) {
                int c0 = quad * 8 + j;
                wf[2 * t][j]     = f32_to_bf16_bits(w[(t * 64 + c0) * 64 + n]);
                wf[2 * t + 1][j] = f32_to_bf16_bits(w[(t * 64 + c0 + 32) * 64 + n]);
            }
        }
    }
    __builtin_amdgcn_sched_barrier(0);  // pin wf loads before the DMAs

    // --- stage chunk g (t = 4g..4g+3) into xs[buf] ---
    // Wave w stages t-plane (4g + w): 16 site-rows as 4 width-16 DMAs.
    // LDS layout: xs[buf][(tl*16 + s)*64 + col'*4], col' = col ^ (s & 7).
    // DMA dest is linear (base + lane*16B), so the SOURCE column is
    // pre-swizzled: lane fetches logical col (lane&15) ^ (row & 7).
#define STAGE(g, buf)                                                          \
    {                                                                          \
        _Pragma("unroll") for (int r = 0; r < 4; r++) {                        \
            int s   = 4 * r + sub;          /* site row within plane */        \
            int col = lcol ^ (s & 7);       /* swizzled 16B column   */        \
            const float* gp = x +                                              \
                ((size_t)((g) * 4 + wave) * NSITES + tile * 16 + s) * 64 +     \
                col * 4;                                                       \
            __builtin_amdgcn_global_load_lds(                                  \
                (const __attribute__((address_space(1))) void*)gp,             \
                (__attribute__((address_space(3))) void*)                      \
                    &xs[buf][(wave * 16 + 4 * r) * 64],                        \
                16, 0, 0);                                                     \
        }                                                                      \
    }

    // --- compute chunk g from xs[buf]: 4 t-planes, 2 MFMA each ---
    // Read with the same XOR: logical col c of row l15 is at c ^ (l15&7).
    // Weights come from wf registers — ZERO VMEM in the loop.
#define COMPUTE(g, buf)                                                        \
    {                                                                          \
        int xr7 = l15 & 7;                                                     \
        _Pragma("unroll") for (int tl = 0; tl < 4; tl++) {                     \
            int t = (g) * 4 + tl;                                              \
            const float* rp = &xs[buf][(tl * 16 + l15) * 64];                  \
            floatx4 f0 = *(const floatx4*)(rp + ((quad * 2) ^ xr7) * 4);       \
            floatx4 f1 = *(const floatx4*)(rp + ((quad * 2 + 1) ^ xr7) * 4);   \
            floatx4 f2 = *(const floatx4*)(rp + (((quad * 2) ^ xr7) + 8) * 4); \
            floatx4 f3 = *(const floatx4*)(rp + (((quad * 2 + 1) ^ xr7) + 8) * 4); \
            bf16x8 a0, a1;                                                     \
            _Pragma("unroll") for (int j = 0; j < 4; j++) {                    \
                a0[j]     = f32_to_bf16_bits(f0[j]);                           \
                a0[j + 4] = f32_to_bf16_bits(f1[j]);                           \
                a1[j]     = f32_to_bf16_bits(f2[j]);                           \
                a1[j + 4] = f32_to_bf16_bits(f3[j]);                           \
            }                                                                  \
            acc[t] = __builtin_amdgcn_mfma_f32_16x16x32_bf16(wf[2 * t], a0,    \
                                                             acc[t], 0, 0, 0); \
            acc[t] = __builtin_amdgcn_mfma_f32_16x16x32_bf16(wf[2 * t + 1], a1,\
                                                             acc[t], 0, 0, 0); \
        }                                                                      \
    }

#define WAITV(N)                                                               \
    asm volatile("s_waitcnt vmcnt(" #N ")" ::: "memory");                      \
    __builtin_amdgcn_s_barrier();                                              \
    __builtin_amdgcn_sched_barrier(0);

    // Prologue: 3 chunks in flight (12 width-16 DMAs/wave) behind the 32 wf
    // loads. Outstanding at first wait: 32 + 12 = 44.
    STAGE(0, 0);
    STAGE(1, 1);
    STAGE(2, 2);

    // Phase 0: vmcnt(8) -> all wf + chunk0 landed (S1,S2 still in flight).
    WAITV(8);
    COMPUTE(0, 0);
    // buf0 consumers done across all waves -> safe to restage into buf0.
    __builtin_amdgcn_s_barrier();
    __builtin_amdgcn_sched_barrier(0);
    STAGE(3, 0);  // outstanding <= 8 + 4 = 12

    // Phase 1: vmcnt(8) -> chunk1 landed (S2, S3 in flight).
    WAITV(8);
    COMPUTE(1, 1);

    // Phase 2: vmcnt(4) -> chunk2 landed (S3 in flight).
    WAITV(4);
    COMPUTE(2, 2);

    // Phase 3: chunk 3 (issued 3 compute-phases ago) fully landed.
    WAITV(0);
    COMPUTE(3, 0);

#undef STAGE
#undef COMPUTE
#undef WAITV

    // Epilogue: one site per thread, 4 consecutive k per reg -> float4 stores.
    int k0   = wave * 16 + quad * 4;
    int site = tile * 16 + l15;
    int b    = site / 784;
    int rem  = site - b * 784;
    int i    = rem / 28;
    int j    = rem - i * 28;
    float* op = out + (size_t)br * OUT_PER_BRANCH +
                (((size_t)(b * 112 + 4 * i)) * 112 + 4 * j) * 64 + k0;
    floatx4 bias4 = *reinterpret_cast<const floatx4*>(bias + k0);

    // Inverse WHT over v (t = 4u+v): acc[4u+q] = sum_v H[q][v] y[4u+v]
#pragma unroll
    for (int u = 0; u < 4; u++) {
        floatx4 y0 = acc[4 * u + 0], y1 = acc[4 * u + 1];
        floatx4 y2 = acc[4 * u + 2], y3 = acc[4 * u + 3];
        floatx4 A = y0 + y2, Bv = y1 + y3, Cv = y0 - y2, Dv = y1 - y3;
        acc[4 * u + 0] = A + Bv;
        acc[4 * u + 1] = A - Bv;
        acc[4 * u + 2] = Cv + Dv;
        acc[4 * u + 3] = Cv - Dv;
    }

    // Inverse WHT over u, then scale + bias + vectorized store (dwordx4).
#pragma unroll
    for (int q = 0; q < 4; q++) {
        floatx4 z0 = acc[0 + q], z1 = acc[4 + q], z2 = acc[8 + q], z3 = acc[12 + q];
        floatx4 A = z0 + z2, Bv = z1 + z3, Cv = z0 - z2, Dv = z1 - z3;
        floatx4 o[4];
        o[0] = A + Bv;
        o[1] = A - Bv;
        o[2] = Cv + Dv;
        o[3] = Cv - Dv;
#pragma unroll
        for (int p = 0; p < 4; p++) {
            floatx4 v = o[p] * 0.0625f + bias4;
            *reinterpret_cast<floatx4*>(op + (size_t)(p * 112 + q) * 64) = v;
        }
    }
}

extern "C" void kernel_launch(void* const* d_in, const int* in_sizes, int n_in,
                              void* d_out, int out_size, void* d_ws, size_t ws_size,
                              hipStream_t stream) {
    const float* x0 = (const float*)d_in[0];
    const float* x1 = (const float*)d_in[1];
    const float* x2 = (const float*)d_in[2];
    const float* w0 = (const float*)d_in[3];
    const float* w1 = (const float*)d_in[4];
    const float* w2 = (const float*)d_in[5];
    const float* b0 = (const float*)d_in[6];
    const float* b1 = (const float*)d_in[7];
    const float* b2 = (const float*)d_in[8];
    float* out = (float*)d_out;
    __hip_bfloat16* wT = (__hip_bfloat16*)d_ws;

    bool use_wt = ws_size >= (size_t)WT_ELEMS * sizeof(__hip_bfloat16);
    if (use_wt) {
        transpose_weights<<<(WT_ELEMS + 255) / 256, 256, 0, stream>>>(w0, w1, w2, wT);
        iwht_kernel<true><<<3 * NTILES, 256, 0, stream>>>(x0, x1, x2, w0, w1, w2, wT,
                                                          b0, b1, b2, out);
    } else {
        iwht_kernel<false><<<3 * NTILES, 256, 0, stream>>>(x0, x1, x2, w0, w1, w2, wT,
                                                           b0, b1, b2, out);
    }
}